// Round 9
// baseline (357.145 us; speedup 1.0000x reference)
//
#include <hip/hip_runtime.h>
#include <math.h>

#define B 4096
#define D 512
#define KC 4096
#define NIDX 131072
#define RR 3
#define TEMP 0.07f
#define M_II 14.5f   // |sim|/0.07 <= ~14.43 incl bf16 slop
#define M_IP 4.0f    // |sim|/density <= ~3.37 incl slop

typedef __bf16 bf16x8 __attribute__((ext_vector_type(8)));
typedef float f32x4 __attribute__((ext_vector_type(4)));

__device__ __forceinline__ void gload_lds16(const void* g, void* l) {
  __builtin_amdgcn_global_load_lds(
      (const __attribute__((address_space(1))) unsigned int*)g,
      (__attribute__((address_space(3))) unsigned int*)l, 16, 0, 0);
}

__device__ __forceinline__ float dot8(float4 a0, float4 a1, float4 b0, float4 b1) {
  return a0.x * b0.x + a0.y * b0.y + a0.z * b0.z + a0.w * b0.w
       + a1.x * b1.x + a1.y * b1.y + a1.z * b1.z + a1.w * b1.w;
}

// ---------------- K1: fused prep: norm->bf16, PAIRED proto gather, rho0 ----------------
// (unchanged — measured ~BW-bound)
__global__ __launch_bounds__(256) void prep_kernel(
    const float* __restrict__ audio, const float* __restrict__ frame,
    const float* __restrict__ a_cent, const float* __restrict__ a_dens,
    const float* __restrict__ f_cent, const float* __restrict__ f_dens,
    const int* __restrict__ vidx, const int* __restrict__ a_i2c,
    const int* __restrict__ f_i2c,
    __bf16* __restrict__ Xa, __bf16* __restrict__ Xf,
    __bf16* __restrict__ Yf, __bf16* __restrict__ Ya,
    float* __restrict__ invdd_f, float* __restrict__ invdd_a,
    float* __restrict__ rho0, float* __restrict__ pcp) {
  const int u = blockIdx.x * 4 + (threadIdx.x >> 6);
  const int lane = threadIdx.x & 63;

  if (u < 2 * B) {
    const float* src; __bf16* dst;
    if (u < B) { src = audio + (size_t)u * D; dst = Xa + (size_t)u * D; }
    else       { src = frame + (size_t)(u - B) * D; dst = Xf + (size_t)(u - B) * D; }
    const float4* s4 = (const float4*)src + lane * 2;
    float4 v0 = s4[0], v1 = s4[1];
    float ss = dot8(v0, v1, v0, v1);
    #pragma unroll
    for (int off = 32; off >= 1; off >>= 1) ss += __shfl_xor(ss, off, 64);
    float invn = 1.f / fmaxf(sqrtf(ss), 1e-12f);
    __bf16 o[8];
    o[0] = (__bf16)(v0.x * invn); o[1] = (__bf16)(v0.y * invn);
    o[2] = (__bf16)(v0.z * invn); o[3] = (__bf16)(v0.w * invn);
    o[4] = (__bf16)(v1.x * invn); o[5] = (__bf16)(v1.y * invn);
    o[6] = (__bf16)(v1.z * invn); o[7] = (__bf16)(v1.w * invn);
    *(bf16x8*)(dst + lane * 8) = *(bf16x8*)o;
  } else if (u < 5 * B) {
    const int q = u - 2 * B;
    const int r = q >> 12;           // /B, B=4096
    const int j = q & (B - 1);
    const int idx = vidx[j];
    const int fp = f_i2c[r * NIDX + idx];
    const int ap = a_i2c[r * NIDX + idx];
    const float4* fr4 = (const float4*)(f_cent + ((size_t)r * KC + fp) * D) + lane * 2;
    const float4* ar4 = (const float4*)(a_cent + ((size_t)r * KC + ap) * D) + lane * 2;
    float4 f0 = fr4[0], f1 = fr4[1];
    float4 a0 = ar4[0], a1 = ar4[1];
    float sf = dot8(f0, f1, f0, f1);
    float sa = dot8(a0, a1, a0, a1);
    float pc = dot8(a0, a1, f0, f1);
    #pragma unroll
    for (int off = 32; off >= 1; off >>= 1) {
      sf += __shfl_xor(sf, off, 64);
      sa += __shfl_xor(sa, off, 64);
      pc += __shfl_xor(pc, off, 64);
    }
    float invnf = 1.f / fmaxf(sqrtf(sf), 1e-12f);
    float invna = 1.f / fmaxf(sqrtf(sa), 1e-12f);
    const int slot = r * B + j;
    __bf16 of[8], oa[8];
    of[0] = (__bf16)(f0.x * invnf); of[1] = (__bf16)(f0.y * invnf);
    of[2] = (__bf16)(f0.z * invnf); of[3] = (__bf16)(f0.w * invnf);
    of[4] = (__bf16)(f1.x * invnf); of[5] = (__bf16)(f1.y * invnf);
    of[6] = (__bf16)(f1.z * invnf); of[7] = (__bf16)(f1.w * invnf);
    oa[0] = (__bf16)(a0.x * invna); oa[1] = (__bf16)(a0.y * invna);
    oa[2] = (__bf16)(a0.z * invna); oa[3] = (__bf16)(a0.w * invna);
    oa[4] = (__bf16)(a1.x * invna); oa[5] = (__bf16)(a1.y * invna);
    oa[6] = (__bf16)(a1.z * invna); oa[7] = (__bf16)(a1.w * invna);
    *(bf16x8*)(Yf + (size_t)slot * D + lane * 8) = *(bf16x8*)of;
    *(bf16x8*)(Ya + (size_t)slot * D + lane * 8) = *(bf16x8*)oa;
    if (lane == 0) {
      invdd_f[slot] = 1.f / f_dens[(size_t)r * KC + fp];
      invdd_a[slot] = 1.f / a_dens[(size_t)r * KC + ap];
      pcp[slot] = pc;
    }
  } else {
    const int i = u - 5 * B;
    const float4* x4 = (const float4*)(audio + (size_t)i * D) + lane * 2;
    const float4* y4 = (const float4*)(frame + (size_t)i * D) + lane * 2;
    float4 a0 = x4[0], a1 = x4[1], f0 = y4[0], f1 = y4[1];
    float saf = dot8(a0, a1, f0, f1);
    float sa = dot8(a0, a1, a0, a1);
    float sf = dot8(f0, f1, f0, f1);
    #pragma unroll
    for (int off = 32; off >= 1; off >>= 1) {
      saf += __shfl_xor(saf, off, 64);
      sa  += __shfl_xor(sa, off, 64);
      sf  += __shfl_xor(sf, off, 64);
    }
    if (lane == 0)
      rho0[i] = saf / (fmaxf(sqrtf(sa), 1e-12f) * fmaxf(sqrtf(sf), 1e-12f));
  }
}

// ---------------- K2 v9: 256x256 tile + 2-phase double-buffered pipeline ----------------
// grid (16, 7, 16): x=row-tile, y=job-slot, z=col-tile. 512 threads, 8 waves.
// Round-8 finding: 128^2/4-blk and 256^2/1-blk both land at exactly 229us,
// MfmaUtil 22% — barrier COUNT is not the cost; the fully-serial step
// (stage -> vmcnt(0) drain -> ds_read -> MFMA, nothing overlapped) is.
// v9 applies the T3-minimum 2-phase recipe at the 256^2 design point:
//   prologue: stage(0)->buf0
//   iter t:   barrier            // drains stage(t), which flew under compute(t-1)
//             stage(t+1)->buf^1  // issue-first, flies under compute(t)
//             compute(t) from buf
// Race-free: stage(t+1) overwrites the buffer last READ at t-1; the top
// barrier's lgkmcnt(0)+vmcnt(0) drain separates them. ROLLED loop + XOR'd
// element offset keeps live scheduling state ~O(1) (rounds 1/2/4/5 failed
// via full-unroll register explosion at the 128-VGPR cliff; here
// __launch_bounds__(512) hard-caps at 256 combined regs -> failure mode is
// visible spills (WRITE_SIZE), not a silent occupancy cliff. Headroom: 4).
__global__ __launch_bounds__(512) void lse_mfma_kernel(
    const __bf16* __restrict__ Xa, const __bf16* __restrict__ Xf,
    const __bf16* __restrict__ Yf, const __bf16* __restrict__ Ya,
    const float* __restrict__ invdd_f, const float* __restrict__ invdd_a,
    float* __restrict__ sp, float* __restrict__ colsp,
    float* __restrict__ diagAll) {
  __shared__ __bf16 As[2 * 256 * 32];  // [buf][row][64B] lane-linear
  __shared__ __bf16 Bs[2 * 256 * 32];
  __shared__ float invL[260];
  __shared__ float part_s[4 * 256];
  __shared__ float colpart[2][256];

  const int yy = blockIdx.y;
  const int job = (yy == 0) ? 0 : yy + 1;
  const int i0 = blockIdx.x * 256;
  const int j0 = blockIdx.z * 256;

  const __bf16* Ab; const __bf16* Bb; const float* invArr = nullptr;
  if (job == 0)      { Ab = Xa; Bb = Xf; }
  else if (job <= 4) { Ab = Xa; Bb = Yf + (size_t)(job - 2) * B * D;
                       invArr = invdd_f + (job - 2) * B; }
  else               { Ab = Xf; Bb = Ya + (size_t)(job - 5) * B * D;
                       invArr = invdd_a + (job - 5) * B; }
  const bool ii = (job == 0);
  const float invT = 1.f / TEMP;
  const float inv0 = ii ? invT : invArr[0];
  const float MJ = ii ? M_II : M_IP;

  const int tid = threadIdx.x;
  const int wv = tid >> 6;             // 0..7
  const int lane = tid & 63;
  const int wr = (wv >> 2) * 128;      // row half: waves 0-3 / 4-7
  const int wc = (wv & 3) * 64;        // col strip: 4 strips of 64
  const int g = lane >> 4;
  const int cl = lane & 15;

  // per-block density tile (written once; K-loop barriers separate from use)
  if (!ii && tid < 258) {
    int idx = j0 + tid; if (idx > B - 1) idx = B - 1;
    invL[tid] = invArr[idx];
  }

  // staging: XOR-swizzled global source so LDS fragment reads are 2-way (free)
  const int srow = lane >> 2;
  const int skoff = (((lane & 3) ^ ((lane >> 3) & 3)) * 16);
  const int c0row = wv * 16 + srow;
  const char* gA0 = (const char*)Ab + (size_t)(i0 + c0row) * (D * 2) + skoff;
  const char* gA1 = gA0 + (size_t)128 * (D * 2);
  const char* gB0 = (const char*)Bb + (size_t)(j0 + c0row) * (D * 2) + skoff;
  const char* gB1 = gB0 + (size_t)128 * (D * 2);
  __bf16* lA0 = As + wv * 512;
  __bf16* lA1 = As + 4096 + wv * 512;
  __bf16* lB0 = Bs + wv * 512;
  __bf16* lB1 = Bs + 4096 + wv * 512;

  const int csw = (g ^ ((cl >> 1) & 3)) * 8;   // swizzled k-chunk for frag reads
  int aoff[8], boff[4];
  #pragma unroll
  for (int t = 0; t < 8; ++t) aoff[t] = (wr + t * 16 + cl) * 32 + csw;
  #pragma unroll
  for (int t = 0; t < 4; ++t) boff[t] = (wc + t * 16 + cl) * 32 + csw;

  f32x4 acc[8][4];
  #pragma unroll
  for (int ri = 0; ri < 8; ++ri)
    #pragma unroll
    for (int ci = 0; ci < 4; ++ci) acc[ri][ci] = (f32x4){0.f, 0.f, 0.f, 0.f};

  // prologue: stage kt=0 into buffer 0
  gload_lds16(gA0, lA0);
  gload_lds16(gA1, lA1);
  gload_lds16(gB0, lB0);
  gload_lds16(gB1, lB1);

  int cur = 0;                          // element offset of active buffer
  for (int kt = 0; kt < 16; ++kt) {
    __syncthreads();                    // drains stage(kt) (flew under kt-1)
    const int nxt = cur ^ 8192;
    if (kt < 15) {
      const int kb = (kt + 1) * 64;     // byte offset within the 1KB row
      gload_lds16(gA0 + kb, lA0 + nxt);
      gload_lds16(gA1 + kb, lA1 + nxt);
      gload_lds16(gB0 + kb, lB0 + nxt);
      gload_lds16(gB1 + kb, lB1 + nxt);
    }
    bf16x8 af[8], bfr[4];
    #pragma unroll
    for (int t = 0; t < 8; ++t) af[t] = *(const bf16x8*)(As + cur + aoff[t]);
    #pragma unroll
    for (int t = 0; t < 4; ++t) bfr[t] = *(const bf16x8*)(Bs + cur + boff[t]);
    #pragma unroll
    for (int ri = 0; ri < 8; ++ri)
      #pragma unroll
      for (int ci = 0; ci < 4; ++ci)
        acc[ri][ci] = __builtin_amdgcn_mfma_f32_16x16x32_bf16(
            af[ri], bfr[ci], acc[ri][ci], 0, 0, 0);
    cur = nxt;
  }

  // ---- single epilogue: fixed-max LSE partials for this tile ----
  const bool dtile = (blockIdx.x == blockIdx.z);   // diagonal intersects tile?
  const int co = (j0 < i0) ? 1 : 0;                // uniform density shift
  float sacc[8][4];
  float csum[4] = {0.f, 0.f, 0.f, 0.f};
  #pragma unroll
  for (int ri = 0; ri < 8; ++ri) {
    #pragma unroll
    for (int v = 0; v < 4; ++v) {
      const int gi = i0 + wr + ri * 16 + g * 4 + v;
      float acc4 = 0.f;
      #pragma unroll
      for (int ci = 0; ci < 4; ++ci) {
        const int jloc = wc + ci * 16 + cl;
        const int gj = j0 + jloc;
        float sc;
        if (ii) sc = invT;
        else if (!dtile) sc = invL[jloc + co];
        else sc = (gj == gi) ? inv0 : invL[(gj < gi) ? (jloc + 1) : jloc];
        float lv = acc[ri][ci][v] * sc;
        if (dtile && gj == gi) diagAll[(size_t)job * B + gi] = lv;
        float ev = __expf(lv - MJ);
        acc4 += ev;
        if (ii) csum[ci] += ev;
      }
      sacc[ri][v] = acc4;
    }
  }
  if (ii) {
    // column partials: reduce over the wave's 128 rows (g-groups), then
    // combine the two row-half wave sets via LDS.
    #pragma unroll
    for (int ci = 0; ci < 4; ++ci) {
      csum[ci] += __shfl_xor(csum[ci], 16, 64);
      csum[ci] += __shfl_xor(csum[ci], 32, 64);
    }
    if (g == 0) {
      #pragma unroll
      for (int ci = 0; ci < 4; ++ci)
        colpart[wv >> 2][wc + ci * 16 + cl] = csum[ci];
    }
    __syncthreads();
    if (tid < 256)
      colsp[(size_t)blockIdx.x * B + j0 + tid] =
          colpart[0][tid] + colpart[1][tid];
  }

  // row-LSE partials: 16-lane column reduce -> LDS -> sum 4 col strips
  #pragma unroll
  for (int ri = 0; ri < 8; ++ri) {
    #pragma unroll
    for (int v = 0; v < 4; ++v) {
      float s = sacc[ri][v];
      #pragma unroll
      for (int off = 8; off >= 1; off >>= 1) s += __shfl_xor(s, off, 64);
      if (cl == 0) part_s[(wv & 3) * 256 + wr + ri * 16 + g * 4 + v] = s;
    }
  }
  __syncthreads();
  if (tid < 256) {
    size_t o = ((size_t)job * 16 + blockIdx.z) * B + i0 + tid;
    sp[o] = part_s[tid] + part_s[256 + tid] + part_s[512 + tid] + part_s[768 + tid];
  }
}

// ---------------- K3: fused LSE-merge (blocks 0..127) + stable rank (128..255) ----------------
__global__ __launch_bounds__(256) void merge_rank_kernel(
    const float* __restrict__ sp, const float* __restrict__ colsp,
    const float* __restrict__ diagAll, const float* __restrict__ rho0,
    const float* __restrict__ pcp,
    float* __restrict__ lossAll, int* __restrict__ rankArr,
    float* __restrict__ srho) {
  __shared__ float lr[B];
  __shared__ float cnt[256];
  const int blk = blockIdx.x;
  const int t = threadIdx.x;
  if (blk < 128) {
    int idx = blk * 256 + t;          // 0 .. 8*B-1
    int job = idx >> 12;
    int i = idx & (B - 1);
    if (job == 1) {
      // f2v inst-inst: column-LSE of job0's matrix; diag equals job0's diag
      float stot = 0.f;
      #pragma unroll
      for (int x = 0; x < 16; ++x) stot += colsp[(size_t)x * B + i];
      lossAll[idx] = M_II + logf(stot) - diagAll[i];
    } else {
      const float* s16 = sp + (size_t)job * 16 * B + i;
      float stot = 0.f;
      #pragma unroll
      for (int x = 0; x < 16; ++x) stot += s16[(size_t)x * B];
      float MJ = (job < 2) ? M_II : M_IP;
      lossAll[idx] = MJ + logf(stot) - diagAll[(size_t)job * B + i];
    }
  } else {
    // rank: 128 blocks x 32 i's, 8-way j-split (512 j's per thread)
    const int base = (blk - 128) * 32;
    const int il = t & 31;
    const int i = base + il;
    const int jlo = (t >> 5) * 512;
    for (int k = t; k < B; k += 256)
      lr[k] = rho0[k] - pcp[k] - pcp[B + k] - pcp[2 * B + k];
    __syncthreads();
    float my = lr[i];
    int rk = 0;
    #pragma unroll 8
    for (int j = jlo; j < jlo + 512; ++j) {
      float v = lr[j];
      rk += (v < my) || (v == my && j < i);   // stable: ties by index
    }
    cnt[t] = (float)rk;
    __syncthreads();
    if (t < 32) {
      int r = 0;
      #pragma unroll
      for (int s = 0; s < 8; ++s) r += (int)cnt[s * 32 + t];
      rankArr[i] = r;
      srho[r] = my;
    }
  }
}

// ---------------- K4: stats + pdf + scan + weights + final (one block, 1024 thr) ----------------
__global__ __launch_bounds__(1024) void cdf_final_kernel(
    const float* __restrict__ srho, const int* __restrict__ rankArr,
    const float* __restrict__ lossAll, float* __restrict__ out) {
  __shared__ float pdf[B];
  __shared__ float wred[16], wr1[16], wr2[16];
  __shared__ float wexc[16];
  __shared__ float mv[3];              // mu, sigma, ylast
  const int t = threadIdx.x;
  const int lane = t & 63;
  const int wid = t >> 6;

  float4 sv = *reinterpret_cast<const float4*>(srho + (size_t)t * 4);
  // ---- mean ----
  float s = sv.x + sv.y + sv.z + sv.w;
  #pragma unroll
  for (int off = 32; off >= 1; off >>= 1) s += __shfl_xor(s, off, 64);
  if (lane == 0) wred[wid] = s;
  __syncthreads();
  if (t == 0) {
    float tot = 0.f;
    #pragma unroll
    for (int w = 0; w < 16; ++w) tot += wred[w];
    mv[0] = tot / (float)B;
  }
  __syncthreads();
  const float mean = mv[0];
  __syncthreads();
  // ---- std ----
  float dx = sv.x - mean, dy = sv.y - mean, dz = sv.z - mean, dw = sv.w - mean;
  float v = dx * dx + dy * dy + dz * dz + dw * dw;
  #pragma unroll
  for (int off = 32; off >= 1; off >>= 1) v += __shfl_xor(v, off, 64);
  if (lane == 0) wred[wid] = v;
  __syncthreads();
  if (t == 0) {
    float tot = 0.f;
    #pragma unroll
    for (int w = 0; w < 16; ++w) tot += wred[w];
    float sd = sqrtf(tot / (float)B);
    mv[0] = mean + 0.3f * sd;          // mu = mean + DELTA*std
    mv[1] = sd * 1.41421356237f;       // sigma = std*sqrt(KA)
  }
  __syncthreads();
  const float mu = mv[0], sg = mv[1];
  const float c = 1.f / (2.5066282746310002f * sg);
  // ---- pdf (in regs) + two-level inclusive scan ----
  float p[4];
  {
    float z0 = (sv.x - mu) / sg; p[0] = expf(-0.5f * z0 * z0) * c;
    float z1 = (sv.y - mu) / sg; p[1] = expf(-0.5f * z1 * z1) * c;
    float z2 = (sv.z - mu) / sg; p[2] = expf(-0.5f * z2 * z2) * c;
    float z3 = (sv.w - mu) / sg; p[3] = expf(-0.5f * z3 * z3) * c;
  }
  float chunk = p[0] + p[1] + p[2] + p[3];
  float incl = chunk;
  #pragma unroll
  for (int d = 1; d < 64; d <<= 1) {
    float n = __shfl_up(incl, d, 64);
    if (lane >= d) incl += n;
  }
  if (lane == 63) wred[wid] = incl;
  __syncthreads();
  if (t == 0) {
    float run = 0.f;
    #pragma unroll
    for (int w = 0; w < 16; ++w) { wexc[w] = run; run += wred[w]; }
    mv[2] = run;                       // ylast = total sum
  }
  __syncthreads();
  float run = wexc[wid] + (incl - chunk);
  #pragma unroll
  for (int e = 0; e < 4; ++e) { run += p[e]; pdf[t * 4 + e] = run; }
  const float ylast = mv[2];
  __syncthreads();
  // ---- final: weights from rank, weighted means, scalar out ----
  int4 rks = *reinterpret_cast<const int4*>(rankArr + (size_t)t * 4);
  float sw = 0.f, s1 = 0.f, s2 = 0.f;
  #pragma unroll
  for (int e = 0; e < 4; ++e) {
    const int i = t * 4 + e;
    const int rk = (e == 0) ? rks.x : (e == 1) ? rks.y : (e == 2) ? rks.z : rks.w;
    float wi = pdf[rk] / ylast;
    float lpv = lossAll[2 * B + i] * (1.f / 27.f) + lossAll[3 * B + i] * (1.f / 9.f)
              + lossAll[4 * B + i] * (1.f / 3.f);
    float lpf = lossAll[5 * B + i] * (1.f / 27.f) + lossAll[6 * B + i] * (1.f / 9.f)
              + lossAll[7 * B + i] * (1.f / 3.f);
    sw += wi;
    s1 += wi * (lossAll[i] + lpv);
    s2 += wi * (lossAll[B + i] + lpf);
  }
  #pragma unroll
  for (int off = 32; off >= 1; off >>= 1) {
    sw += __shfl_xor(sw, off, 64);
    s1 += __shfl_xor(s1, off, 64);
    s2 += __shfl_xor(s2, off, 64);
  }
  if (lane == 0) { wred[wid] = sw; wr1[wid] = s1; wr2[wid] = s2; }
  __syncthreads();
  if (t == 0) {
    float tw = 0.f, t1 = 0.f, t2 = 0.f;
    #pragma unroll
    for (int w = 0; w < 16; ++w) { tw += wred[w]; t1 += wr1[w]; t2 += wr2[w]; }
    out[0] = t1 / tw + t2 / tw;
  }
}

extern "C" void kernel_launch(void* const* d_in, const int* in_sizes, int n_in,
                              void* d_out, int out_size, void* d_ws, size_t ws_size,
                              hipStream_t stream) {
  const float* audio  = (const float*)d_in[0];
  const float* frame  = (const float*)d_in[1];
  const float* a_cent = (const float*)d_in[2];
  const float* a_dens = (const float*)d_in[3];
  const float* f_cent = (const float*)d_in[4];
  const float* f_dens = (const float*)d_in[5];
  const int* vidx  = (const int*)d_in[6];
  const int* a_i2c = (const int*)d_in[7];
  const int* f_i2c = (const int*)d_in[8];
  float* out = (float*)d_out;

  const size_t BD = (size_t)B * D;
  char* base = (char*)d_ws;
  __bf16* Xa = (__bf16*)base;              base += BD * 2;
  __bf16* Xf = (__bf16*)base;              base += BD * 2;
  __bf16* Yf = (__bf16*)base;              base += 3 * BD * 2;
  __bf16* Ya = (__bf16*)base;              base += 3 * BD * 2;
  float* invdd_f = (float*)base;           base += 3 * B * 4;
  float* invdd_a = (float*)base;           base += 3 * B * 4;
  float* rho0    = (float*)base;           base += B * 4;
  float* pcp     = (float*)base;           base += 3 * B * 4;
  float* sp      = (float*)base;           base += 128 * B * 4;
  float* colsp   = (float*)base;           base += 16 * B * 4;
  float* diagAll = (float*)base;           base += 8 * B * 4;
  float* lossAll = (float*)base;           base += 8 * B * 4;
  float* srho    = (float*)base;           base += B * 4;
  int*   rankArr = (int*)base;

  prep_kernel<<<(6 * B) / 4, 256, 0, stream>>>(audio, frame, a_cent, a_dens,
                                               f_cent, f_dens, vidx, a_i2c, f_i2c,
                                               Xa, Xf, Yf, Ya, invdd_f, invdd_a,
                                               rho0, pcp);

  dim3 g2(16, 7, 16);
  lse_mfma_kernel<<<g2, 512, 0, stream>>>(Xa, Xf, Yf, Ya, invdd_f, invdd_a,
                                          sp, colsp, diagAll);

  merge_rank_kernel<<<256, 256, 0, stream>>>(sp, colsp, diagAll, rho0, pcp,
                                             lossAll, rankArr, srho);
  cdf_final_kernel<<<1, 1024, 0, stream>>>(srho, rankArr, lossAll, out);
}

// Round 11
// 348.728 us; speedup vs baseline: 1.0241x; 1.0241x over previous
//
#include <hip/hip_runtime.h>
#include <math.h>

#define B 4096
#define D 512
#define KC 4096
#define NIDX 131072
#define RR 3
#define TEMP 0.07f
#define M_II 14.5f   // |sim|/0.07 <= ~14.43 incl bf16 slop
#define M_IP 4.0f    // |sim|/density <= ~3.37 incl slop

typedef __bf16 bf16x8 __attribute__((ext_vector_type(8)));
typedef float f32x4 __attribute__((ext_vector_type(4)));

__device__ __forceinline__ void gload_lds16(const void* g, void* l) {
  __builtin_amdgcn_global_load_lds(
      (const __attribute__((address_space(1))) unsigned int*)g,
      (__attribute__((address_space(3))) unsigned int*)l, 16, 0, 0);
}

__device__ __forceinline__ float dot8(float4 a0, float4 a1, float4 b0, float4 b1) {
  return a0.x * b0.x + a0.y * b0.y + a0.z * b0.z + a0.w * b0.w
       + a1.x * b1.x + a1.y * b1.y + a1.z * b1.z + a1.w * b1.w;
}

// ---------------- K1: fused prep: norm->bf16, PAIRED proto gather, rho0 ----------------
// (unchanged — measured ~BW-bound)
__global__ __launch_bounds__(256) void prep_kernel(
    const float* __restrict__ audio, const float* __restrict__ frame,
    const float* __restrict__ a_cent, const float* __restrict__ a_dens,
    const float* __restrict__ f_cent, const float* __restrict__ f_dens,
    const int* __restrict__ vidx, const int* __restrict__ a_i2c,
    const int* __restrict__ f_i2c,
    __bf16* __restrict__ Xa, __bf16* __restrict__ Xf,
    __bf16* __restrict__ Yf, __bf16* __restrict__ Ya,
    float* __restrict__ invdd_f, float* __restrict__ invdd_a,
    float* __restrict__ rho0, float* __restrict__ pcp) {
  const int u = blockIdx.x * 4 + (threadIdx.x >> 6);
  const int lane = threadIdx.x & 63;

  if (u < 2 * B) {
    const float* src; __bf16* dst;
    if (u < B) { src = audio + (size_t)u * D; dst = Xa + (size_t)u * D; }
    else       { src = frame + (size_t)(u - B) * D; dst = Xf + (size_t)(u - B) * D; }
    const float4* s4 = (const float4*)src + lane * 2;
    float4 v0 = s4[0], v1 = s4[1];
    float ss = dot8(v0, v1, v0, v1);
    #pragma unroll
    for (int off = 32; off >= 1; off >>= 1) ss += __shfl_xor(ss, off, 64);
    float invn = 1.f / fmaxf(sqrtf(ss), 1e-12f);
    __bf16 o[8];
    o[0] = (__bf16)(v0.x * invn); o[1] = (__bf16)(v0.y * invn);
    o[2] = (__bf16)(v0.z * invn); o[3] = (__bf16)(v0.w * invn);
    o[4] = (__bf16)(v1.x * invn); o[5] = (__bf16)(v1.y * invn);
    o[6] = (__bf16)(v1.z * invn); o[7] = (__bf16)(v1.w * invn);
    *(bf16x8*)(dst + lane * 8) = *(bf16x8*)o;
  } else if (u < 5 * B) {
    const int q = u - 2 * B;
    const int r = q >> 12;           // /B, B=4096
    const int j = q & (B - 1);
    const int idx = vidx[j];
    const int fp = f_i2c[r * NIDX + idx];
    const int ap = a_i2c[r * NIDX + idx];
    const float4* fr4 = (const float4*)(f_cent + ((size_t)r * KC + fp) * D) + lane * 2;
    const float4* ar4 = (const float4*)(a_cent + ((size_t)r * KC + ap) * D) + lane * 2;
    float4 f0 = fr4[0], f1 = fr4[1];
    float4 a0 = ar4[0], a1 = ar4[1];
    float sf = dot8(f0, f1, f0, f1);
    float sa = dot8(a0, a1, a0, a1);
    float pc = dot8(a0, a1, f0, f1);
    #pragma unroll
    for (int off = 32; off >= 1; off >>= 1) {
      sf += __shfl_xor(sf, off, 64);
      sa += __shfl_xor(sa, off, 64);
      pc += __shfl_xor(pc, off, 64);
    }
    float invnf = 1.f / fmaxf(sqrtf(sf), 1e-12f);
    float invna = 1.f / fmaxf(sqrtf(sa), 1e-12f);
    const int slot = r * B + j;
    __bf16 of[8], oa[8];
    of[0] = (__bf16)(f0.x * invnf); of[1] = (__bf16)(f0.y * invnf);
    of[2] = (__bf16)(f0.z * invnf); of[3] = (__bf16)(f0.w * invnf);
    of[4] = (__bf16)(f1.x * invnf); of[5] = (__bf16)(f1.y * invnf);
    of[6] = (__bf16)(f1.z * invnf); of[7] = (__bf16)(f1.w * invnf);
    oa[0] = (__bf16)(a0.x * invna); oa[1] = (__bf16)(a0.y * invna);
    oa[2] = (__bf16)(a0.z * invna); oa[3] = (__bf16)(a0.w * invna);
    oa[4] = (__bf16)(a1.x * invna); oa[5] = (__bf16)(a1.y * invna);
    oa[6] = (__bf16)(a1.z * invna); oa[7] = (__bf16)(a1.w * invna);
    *(bf16x8*)(Yf + (size_t)slot * D + lane * 8) = *(bf16x8*)of;
    *(bf16x8*)(Ya + (size_t)slot * D + lane * 8) = *(bf16x8*)oa;
    if (lane == 0) {
      invdd_f[slot] = 1.f / f_dens[(size_t)r * KC + fp];
      invdd_a[slot] = 1.f / a_dens[(size_t)r * KC + ap];
      pcp[slot] = pc;
    }
  } else {
    const int i = u - 5 * B;
    const float4* x4 = (const float4*)(audio + (size_t)i * D) + lane * 2;
    const float4* y4 = (const float4*)(frame + (size_t)i * D) + lane * 2;
    float4 a0 = x4[0], a1 = x4[1], f0 = y4[0], f1 = y4[1];
    float saf = dot8(a0, a1, f0, f1);
    float sa = dot8(a0, a1, a0, a1);
    float sf = dot8(f0, f1, f0, f1);
    #pragma unroll
    for (int off = 32; off >= 1; off >>= 1) {
      saf += __shfl_xor(saf, off, 64);
      sa  += __shfl_xor(sa, off, 64);
      sf  += __shfl_xor(sf, off, 64);
    }
    if (lane == 0)
      rho0[i] = saf / (fmaxf(sqrtf(sa), 1e-12f) * fmaxf(sqrtf(sf), 1e-12f));
  }
}

// ---------------- K2 v10: 256x256 tile (v8 body) + XCD-aware slab swizzle ----------------
// 1792 blocks, 1-D. Round-9 finding: FETCH_SIZE = 131MB vs 33.5MB of input =
// 4x HBM over-fetch at 570 GB/s sustained — K2's duration IS its memory-miss
// traffic. Cause: (16,7,16) grid round-robins across 8 XCDs, so the 16 blocks
// sharing an A-panel (and 16 sharing a B-panel) sit on DIFFERENT XCDs and
// miss concurrently (L2s not shared, L3 not yet filled) -> every stage step
// pays ~900cyc HBM latency; depth-1 prefetch (v9) covers only ~300-500cyc,
// which is why it was neutral.
// Fix (T1): XCD k (= blockIdx.x & 7 under round-robin dispatch) owns
// contiguous 4x4-tile slabs: 4 A-panels (1MB) + 4 B-panels (1MB) = 2MB,
// 4x L2 reuse per panel; ~32 resident blocks/XCD = 2 slabs = 4MB = L2-sized.
// 1792 = 8 XCDs x 14 slabs x 16 blocks. K-loop body is VERBATIM v8 (228.9us,
// 124 VGPR, no spills); only scalar index math changed.
// (Round 10 was an infra failure — "container failed twice", no measurement;
// resubmitted unchanged. Decomposition re-verified bijective offline.)
__global__ __launch_bounds__(512) void lse_mfma_kernel(
    const __bf16* __restrict__ Xa, const __bf16* __restrict__ Xf,
    const __bf16* __restrict__ Yf, const __bf16* __restrict__ Ya,
    const float* __restrict__ invdd_f, const float* __restrict__ invdd_a,
    float* __restrict__ sp, float* __restrict__ colsp,
    float* __restrict__ diagAll) {
  __shared__ __bf16 As[256 * 32];      // [row][64B] lane-linear (glds constraint)
  __shared__ __bf16 Bs[256 * 32];
  __shared__ float invL[260];
  __shared__ float part_s[4 * 256];
  __shared__ float colpart[2][256];

  // ---- XCD slab decomposition ----
  const int b = blockIdx.x;
  const int xcd = b & 7;
  const int bi = b >> 3;               // 0..223 per XCD
  const int slab = bi >> 4;            // 0..13
  const int w = bi & 15;
  const int gs = xcd * 14 + slab;      // global slab 0..111
  const int yy = gs >> 4;              // job slot 0..6
  const int s = gs & 15;
  const int bx = (s >> 2) * 4 + (w >> 2);   // row-tile 0..15
  const int bz = (s & 3) * 4 + (w & 3);     // col-tile 0..15

  const int job = (yy == 0) ? 0 : yy + 1;
  const int i0 = bx * 256;
  const int j0 = bz * 256;

  const __bf16* Ab; const __bf16* Bb; const float* invArr = nullptr;
  if (job == 0)      { Ab = Xa; Bb = Xf; }
  else if (job <= 4) { Ab = Xa; Bb = Yf + (size_t)(job - 2) * B * D;
                       invArr = invdd_f + (job - 2) * B; }
  else               { Ab = Xf; Bb = Ya + (size_t)(job - 5) * B * D;
                       invArr = invdd_a + (job - 5) * B; }
  const bool ii = (job == 0);
  const float invT = 1.f / TEMP;
  const float inv0 = ii ? invT : invArr[0];
  const float MJ = ii ? M_II : M_IP;

  const int tid = threadIdx.x;
  const int wv = tid >> 6;             // 0..7
  const int lane = tid & 63;
  const int wr = (wv >> 2) * 128;      // row half: waves 0-3 / 4-7
  const int wc = (wv & 3) * 64;        // col strip: 4 strips of 64
  const int g = lane >> 4;
  const int cl = lane & 15;

  // per-block density tile (written once; K-loop barriers separate from use)
  if (!ii && tid < 258) {
    int idx = j0 + tid; if (idx > B - 1) idx = B - 1;
    invL[tid] = invArr[idx];
  }

  // staging: XOR-swizzled global source so LDS fragment reads are 2-way (free)
  const int srow = lane >> 2;
  const int skoff = (((lane & 3) ^ ((lane >> 3) & 3)) * 16);
  const int c0row = wv * 16 + srow;
  const char* gA0 = (const char*)Ab + (size_t)(i0 + c0row) * (D * 2) + skoff;
  const char* gA1 = gA0 + (size_t)128 * (D * 2);
  const char* gB0 = (const char*)Bb + (size_t)(j0 + c0row) * (D * 2) + skoff;
  const char* gB1 = gB0 + (size_t)128 * (D * 2);
  __bf16* lA0 = As + wv * 512;
  __bf16* lA1 = As + 4096 + wv * 512;
  __bf16* lB0 = Bs + wv * 512;
  __bf16* lB1 = Bs + 4096 + wv * 512;

  const int csw = (g ^ ((cl >> 1) & 3)) * 8;   // swizzled k-chunk for frag reads
  int aoff[8], boff[4];
  #pragma unroll
  for (int t = 0; t < 8; ++t) aoff[t] = (wr + t * 16 + cl) * 32 + csw;
  #pragma unroll
  for (int t = 0; t < 4; ++t) boff[t] = (wc + t * 16 + cl) * 32 + csw;

  f32x4 acc[8][4];
  #pragma unroll
  for (int ri = 0; ri < 8; ++ri)
    #pragma unroll
    for (int ci = 0; ci < 4; ++ci) acc[ri][ci] = (f32x4){0.f, 0.f, 0.f, 0.f};

  for (int kt = 0; kt < 16; ++kt) {
    __syncthreads();
    const int kb = kt * 64;
    gload_lds16(gA0 + kb, lA0);
    gload_lds16(gA1 + kb, lA1);
    gload_lds16(gB0 + kb, lB0);
    gload_lds16(gB1 + kb, lB1);
    __syncthreads();
    bf16x8 af[8], bfr[4];
    #pragma unroll
    for (int t = 0; t < 8; ++t) af[t] = *(const bf16x8*)(As + aoff[t]);
    #pragma unroll
    for (int t = 0; t < 4; ++t) bfr[t] = *(const bf16x8*)(Bs + boff[t]);
    #pragma unroll
    for (int ri = 0; ri < 8; ++ri)
      #pragma unroll
      for (int ci = 0; ci < 4; ++ci)
        acc[ri][ci] = __builtin_amdgcn_mfma_f32_16x16x32_bf16(
            af[ri], bfr[ci], acc[ri][ci], 0, 0, 0);
  }

  // ---- single epilogue: fixed-max LSE partials for this tile ----
  const bool dtile = (bx == bz);                   // diagonal intersects tile?
  const int co = (j0 < i0) ? 1 : 0;                // uniform density shift
  float sacc[8][4];
  float csum[4] = {0.f, 0.f, 0.f, 0.f};
  #pragma unroll
  for (int ri = 0; ri < 8; ++ri) {
    #pragma unroll
    for (int v = 0; v < 4; ++v) {
      const int gi = i0 + wr + ri * 16 + g * 4 + v;
      float acc4 = 0.f;
      #pragma unroll
      for (int ci = 0; ci < 4; ++ci) {
        const int jloc = wc + ci * 16 + cl;
        const int gj = j0 + jloc;
        float sc;
        if (ii) sc = invT;
        else if (!dtile) sc = invL[jloc + co];
        else sc = (gj == gi) ? inv0 : invL[(gj < gi) ? (jloc + 1) : jloc];
        float lv = acc[ri][ci][v] * sc;
        if (dtile && gj == gi) diagAll[(size_t)job * B + gi] = lv;
        float ev = __expf(lv - MJ);
        acc4 += ev;
        if (ii) csum[ci] += ev;
      }
      sacc[ri][v] = acc4;
    }
  }
  if (ii) {
    // column partials: reduce over the wave's 128 rows (g-groups), then
    // combine the two row-half wave sets via LDS.
    #pragma unroll
    for (int ci = 0; ci < 4; ++ci) {
      csum[ci] += __shfl_xor(csum[ci], 16, 64);
      csum[ci] += __shfl_xor(csum[ci], 32, 64);
    }
    if (g == 0) {
      #pragma unroll
      for (int ci = 0; ci < 4; ++ci)
        colpart[wv >> 2][wc + ci * 16 + cl] = csum[ci];
    }
    __syncthreads();
    if (tid < 256)
      colsp[(size_t)bx * B + j0 + tid] =
          colpart[0][tid] + colpart[1][tid];
  }

  // row-LSE partials: 16-lane column reduce -> LDS -> sum 4 col strips
  #pragma unroll
  for (int ri = 0; ri < 8; ++ri) {
    #pragma unroll
    for (int v = 0; v < 4; ++v) {
      float s2 = sacc[ri][v];
      #pragma unroll
      for (int off = 8; off >= 1; off >>= 1) s2 += __shfl_xor(s2, off, 64);
      if (cl == 0) part_s[(wv & 3) * 256 + wr + ri * 16 + g * 4 + v] = s2;
    }
  }
  __syncthreads();
  if (tid < 256) {
    size_t o = ((size_t)job * 16 + bz) * B + i0 + tid;
    sp[o] = part_s[tid] + part_s[256 + tid] + part_s[512 + tid] + part_s[768 + tid];
  }
}

// ---------------- K3: fused LSE-merge (blocks 0..127) + stable rank (128..255) ----------------
__global__ __launch_bounds__(256) void merge_rank_kernel(
    const float* __restrict__ sp, const float* __restrict__ colsp,
    const float* __restrict__ diagAll, const float* __restrict__ rho0,
    const float* __restrict__ pcp,
    float* __restrict__ lossAll, int* __restrict__ rankArr,
    float* __restrict__ srho) {
  __shared__ float lr[B];
  __shared__ float cnt[256];
  const int blk = blockIdx.x;
  const int t = threadIdx.x;
  if (blk < 128) {
    int idx = blk * 256 + t;          // 0 .. 8*B-1
    int job = idx >> 12;
    int i = idx & (B - 1);
    if (job == 1) {
      // f2v inst-inst: column-LSE of job0's matrix; diag equals job0's diag
      float stot = 0.f;
      #pragma unroll
      for (int x = 0; x < 16; ++x) stot += colsp[(size_t)x * B + i];
      lossAll[idx] = M_II + logf(stot) - diagAll[i];
    } else {
      const float* s16 = sp + (size_t)job * 16 * B + i;
      float stot = 0.f;
      #pragma unroll
      for (int x = 0; x < 16; ++x) stot += s16[(size_t)x * B];
      float MJ = (job < 2) ? M_II : M_IP;
      lossAll[idx] = MJ + logf(stot) - diagAll[(size_t)job * B + i];
    }
  } else {
    // rank: 128 blocks x 32 i's, 8-way j-split (512 j's per thread)
    const int base = (blk - 128) * 32;
    const int il = t & 31;
    const int i = base + il;
    const int jlo = (t >> 5) * 512;
    for (int k = t; k < B; k += 256)
      lr[k] = rho0[k] - pcp[k] - pcp[B + k] - pcp[2 * B + k];
    __syncthreads();
    float my = lr[i];
    int rk = 0;
    #pragma unroll 8
    for (int j = jlo; j < jlo + 512; ++j) {
      float v = lr[j];
      rk += (v < my) || (v == my && j < i);   // stable: ties by index
    }
    cnt[t] = (float)rk;
    __syncthreads();
    if (t < 32) {
      int r = 0;
      #pragma unroll
      for (int s = 0; s < 8; ++s) r += (int)cnt[s * 32 + t];
      rankArr[i] = r;
      srho[r] = my;
    }
  }
}

// ---------------- K4: stats + pdf + scan + weights + final (one block, 1024 thr) ----------------
__global__ __launch_bounds__(1024) void cdf_final_kernel(
    const float* __restrict__ srho, const int* __restrict__ rankArr,
    const float* __restrict__ lossAll, float* __restrict__ out) {
  __shared__ float pdf[B];
  __shared__ float wred[16], wr1[16], wr2[16];
  __shared__ float wexc[16];
  __shared__ float mv[3];              // mu, sigma, ylast
  const int t = threadIdx.x;
  const int lane = t & 63;
  const int wid = t >> 6;

  float4 sv = *reinterpret_cast<const float4*>(srho + (size_t)t * 4);
  // ---- mean ----
  float s = sv.x + sv.y + sv.z + sv.w;
  #pragma unroll
  for (int off = 32; off >= 1; off >>= 1) s += __shfl_xor(s, off, 64);
  if (lane == 0) wred[wid] = s;
  __syncthreads();
  if (t == 0) {
    float tot = 0.f;
    #pragma unroll
    for (int w = 0; w < 16; ++w) tot += wred[w];
    mv[0] = tot / (float)B;
  }
  __syncthreads();
  const float mean = mv[0];
  __syncthreads();
  // ---- std ----
  float dx = sv.x - mean, dy = sv.y - mean, dz = sv.z - mean, dw = sv.w - mean;
  float v = dx * dx + dy * dy + dz * dz + dw * dw;
  #pragma unroll
  for (int off = 32; off >= 1; off >>= 1) v += __shfl_xor(v, off, 64);
  if (lane == 0) wred[wid] = v;
  __syncthreads();
  if (t == 0) {
    float tot = 0.f;
    #pragma unroll
    for (int w = 0; w < 16; ++w) tot += wred[w];
    float sd = sqrtf(tot / (float)B);
    mv[0] = mean + 0.3f * sd;          // mu = mean + DELTA*std
    mv[1] = sd * 1.41421356237f;       // sigma = std*sqrt(KA)
  }
  __syncthreads();
  const float mu = mv[0], sg = mv[1];
  const float c = 1.f / (2.5066282746310002f * sg);
  // ---- pdf (in regs) + two-level inclusive scan ----
  float p[4];
  {
    float z0 = (sv.x - mu) / sg; p[0] = expf(-0.5f * z0 * z0) * c;
    float z1 = (sv.y - mu) / sg; p[1] = expf(-0.5f * z1 * z1) * c;
    float z2 = (sv.z - mu) / sg; p[2] = expf(-0.5f * z2 * z2) * c;
    float z3 = (sv.w - mu) / sg; p[3] = expf(-0.5f * z3 * z3) * c;
  }
  float chunk = p[0] + p[1] + p[2] + p[3];
  float incl = chunk;
  #pragma unroll
  for (int d = 1; d < 64; d <<= 1) {
    float n = __shfl_up(incl, d, 64);
    if (lane >= d) incl += n;
  }
  if (lane == 63) wred[wid] = incl;
  __syncthreads();
  if (t == 0) {
    float run = 0.f;
    #pragma unroll
    for (int w = 0; w < 16; ++w) { wexc[w] = run; run += wred[w]; }
    mv[2] = run;                       // ylast = total sum
  }
  __syncthreads();
  float run = wexc[wid] + (incl - chunk);
  #pragma unroll
  for (int e = 0; e < 4; ++e) { run += p[e]; pdf[t * 4 + e] = run; }
  const float ylast = mv[2];
  __syncthreads();
  // ---- final: weights from rank, weighted means, scalar out ----
  int4 rks = *reinterpret_cast<const int4*>(rankArr + (size_t)t * 4);
  float sw = 0.f, s1 = 0.f, s2 = 0.f;
  #pragma unroll
  for (int e = 0; e < 4; ++e) {
    const int i = t * 4 + e;
    const int rk = (e == 0) ? rks.x : (e == 1) ? rks.y : (e == 2) ? rks.z : rks.w;
    float wi = pdf[rk] / ylast;
    float lpv = lossAll[2 * B + i] * (1.f / 27.f) + lossAll[3 * B + i] * (1.f / 9.f)
              + lossAll[4 * B + i] * (1.f / 3.f);
    float lpf = lossAll[5 * B + i] * (1.f / 27.f) + lossAll[6 * B + i] * (1.f / 9.f)
              + lossAll[7 * B + i] * (1.f / 3.f);
    sw += wi;
    s1 += wi * (lossAll[i] + lpv);
    s2 += wi * (lossAll[B + i] + lpf);
  }
  #pragma unroll
  for (int off = 32; off >= 1; off >>= 1) {
    sw += __shfl_xor(sw, off, 64);
    s1 += __shfl_xor(s1, off, 64);
    s2 += __shfl_xor(s2, off, 64);
  }
  if (lane == 0) { wred[wid] = sw; wr1[wid] = s1; wr2[wid] = s2; }
  __syncthreads();
  if (t == 0) {
    float tw = 0.f, t1 = 0.f, t2 = 0.f;
    #pragma unroll
    for (int w = 0; w < 16; ++w) { tw += wred[w]; t1 += wr1[w]; t2 += wr2[w]; }
    out[0] = t1 / tw + t2 / tw;
  }
}

extern "C" void kernel_launch(void* const* d_in, const int* in_sizes, int n_in,
                              void* d_out, int out_size, void* d_ws, size_t ws_size,
                              hipStream_t stream) {
  const float* audio  = (const float*)d_in[0];
  const float* frame  = (const float*)d_in[1];
  const float* a_cent = (const float*)d_in[2];
  const float* a_dens = (const float*)d_in[3];
  const float* f_cent = (const float*)d_in[4];
  const float* f_dens = (const float*)d_in[5];
  const int* vidx  = (const int*)d_in[6];
  const int* a_i2c = (const int*)d_in[7];
  const int* f_i2c = (const int*)d_in[8];
  float* out = (float*)d_out;

  const size_t BD = (size_t)B * D;
  char* base = (char*)d_ws;
  __bf16* Xa = (__bf16*)base;              base += BD * 2;
  __bf16* Xf = (__bf16*)base;              base += BD * 2;
  __bf16* Yf = (__bf16*)base;              base += 3 * BD * 2;
  __bf16* Ya = (__bf16*)base;              base += 3 * BD * 2;
  float* invdd_f = (float*)base;           base += 3 * B * 4;
  float* invdd_a = (float*)base;           base += 3 * B * 4;
  float* rho0    = (float*)base;           base += B * 4;
  float* pcp     = (float*)base;           base += 3 * B * 4;
  float* sp      = (float*)base;           base += 128 * B * 4;
  float* colsp   = (float*)base;           base += 16 * B * 4;
  float* diagAll = (float*)base;           base += 8 * B * 4;
  float* lossAll = (float*)base;           base += 8 * B * 4;
  float* srho    = (float*)base;           base += B * 4;
  int*   rankArr = (int*)base;

  prep_kernel<<<(6 * B) / 4, 256, 0, stream>>>(audio, frame, a_cent, a_dens,
                                               f_cent, f_dens, vidx, a_i2c, f_i2c,
                                               Xa, Xf, Yf, Ya, invdd_f, invdd_a,
                                               rho0, pcp);

  lse_mfma_kernel<<<1792, 512, 0, stream>>>(Xa, Xf, Yf, Ya, invdd_f, invdd_a,
                                            sp, colsp, diagAll);

  merge_rank_kernel<<<256, 256, 0, stream>>>(sp, colsp, diagAll, rho0, pcp,
                                             lossAll, rankArr, srho);
  cdf_final_kernel<<<1, 1024, 0, stream>>>(srho, rankArr, lossAll, out);
}

// Round 12
// 345.178 us; speedup vs baseline: 1.0347x; 1.0103x over previous
//
#include <hip/hip_runtime.h>
#include <math.h>

#define B 4096
#define D 512
#define KC 4096
#define NIDX 131072
#define RR 3
#define TEMP 0.07f
#define M_II 14.5f   // |sim|/0.07 <= ~14.43 incl bf16 slop
#define M_IP 4.0f    // |sim|/density <= ~3.37 incl slop

typedef __bf16 bf16x8 __attribute__((ext_vector_type(8)));
typedef float f32x4 __attribute__((ext_vector_type(4)));

__device__ __forceinline__ void gload_lds16(const void* g, void* l) {
  __builtin_amdgcn_global_load_lds(
      (const __attribute__((address_space(1))) unsigned int*)g,
      (__attribute__((address_space(3))) unsigned int*)l, 16, 0, 0);
}

__device__ __forceinline__ float dot8(float4 a0, float4 a1, float4 b0, float4 b1) {
  return a0.x * b0.x + a0.y * b0.y + a0.z * b0.z + a0.w * b0.w
       + a1.x * b1.x + a1.y * b1.y + a1.z * b1.z + a1.w * b1.w;
}

// ---------------- K1: fused prep: norm->bf16, PAIRED proto gather, rho0 ----------------
// (unchanged — measured ~BW-bound)
__global__ __launch_bounds__(256) void prep_kernel(
    const float* __restrict__ audio, const float* __restrict__ frame,
    const float* __restrict__ a_cent, const float* __restrict__ a_dens,
    const float* __restrict__ f_cent, const float* __restrict__ f_dens,
    const int* __restrict__ vidx, const int* __restrict__ a_i2c,
    const int* __restrict__ f_i2c,
    __bf16* __restrict__ Xa, __bf16* __restrict__ Xf,
    __bf16* __restrict__ Yf, __bf16* __restrict__ Ya,
    float* __restrict__ invdd_f, float* __restrict__ invdd_a,
    float* __restrict__ rho0, float* __restrict__ pcp) {
  const int u = blockIdx.x * 4 + (threadIdx.x >> 6);
  const int lane = threadIdx.x & 63;

  if (u < 2 * B) {
    const float* src; __bf16* dst;
    if (u < B) { src = audio + (size_t)u * D; dst = Xa + (size_t)u * D; }
    else       { src = frame + (size_t)(u - B) * D; dst = Xf + (size_t)(u - B) * D; }
    const float4* s4 = (const float4*)src + lane * 2;
    float4 v0 = s4[0], v1 = s4[1];
    float ss = dot8(v0, v1, v0, v1);
    #pragma unroll
    for (int off = 32; off >= 1; off >>= 1) ss += __shfl_xor(ss, off, 64);
    float invn = 1.f / fmaxf(sqrtf(ss), 1e-12f);
    __bf16 o[8];
    o[0] = (__bf16)(v0.x * invn); o[1] = (__bf16)(v0.y * invn);
    o[2] = (__bf16)(v0.z * invn); o[3] = (__bf16)(v0.w * invn);
    o[4] = (__bf16)(v1.x * invn); o[5] = (__bf16)(v1.y * invn);
    o[6] = (__bf16)(v1.z * invn); o[7] = (__bf16)(v1.w * invn);
    *(bf16x8*)(dst + lane * 8) = *(bf16x8*)o;
  } else if (u < 5 * B) {
    const int q = u - 2 * B;
    const int r = q >> 12;           // /B, B=4096
    const int j = q & (B - 1);
    const int idx = vidx[j];
    const int fp = f_i2c[r * NIDX + idx];
    const int ap = a_i2c[r * NIDX + idx];
    const float4* fr4 = (const float4*)(f_cent + ((size_t)r * KC + fp) * D) + lane * 2;
    const float4* ar4 = (const float4*)(a_cent + ((size_t)r * KC + ap) * D) + lane * 2;
    float4 f0 = fr4[0], f1 = fr4[1];
    float4 a0 = ar4[0], a1 = ar4[1];
    float sf = dot8(f0, f1, f0, f1);
    float sa = dot8(a0, a1, a0, a1);
    float pc = dot8(a0, a1, f0, f1);
    #pragma unroll
    for (int off = 32; off >= 1; off >>= 1) {
      sf += __shfl_xor(sf, off, 64);
      sa += __shfl_xor(sa, off, 64);
      pc += __shfl_xor(pc, off, 64);
    }
    float invnf = 1.f / fmaxf(sqrtf(sf), 1e-12f);
    float invna = 1.f / fmaxf(sqrtf(sa), 1e-12f);
    const int slot = r * B + j;
    __bf16 of[8], oa[8];
    of[0] = (__bf16)(f0.x * invnf); of[1] = (__bf16)(f0.y * invnf);
    of[2] = (__bf16)(f0.z * invnf); of[3] = (__bf16)(f0.w * invnf);
    of[4] = (__bf16)(f1.x * invnf); of[5] = (__bf16)(f1.y * invnf);
    of[6] = (__bf16)(f1.z * invnf); of[7] = (__bf16)(f1.w * invnf);
    oa[0] = (__bf16)(a0.x * invna); oa[1] = (__bf16)(a0.y * invna);
    oa[2] = (__bf16)(a0.z * invna); oa[3] = (__bf16)(a0.w * invna);
    oa[4] = (__bf16)(a1.x * invna); oa[5] = (__bf16)(a1.y * invna);
    oa[6] = (__bf16)(a1.z * invna); oa[7] = (__bf16)(a1.w * invna);
    *(bf16x8*)(Yf + (size_t)slot * D + lane * 8) = *(bf16x8*)of;
    *(bf16x8*)(Ya + (size_t)slot * D + lane * 8) = *(bf16x8*)oa;
    if (lane == 0) {
      invdd_f[slot] = 1.f / f_dens[(size_t)r * KC + fp];
      invdd_a[slot] = 1.f / a_dens[(size_t)r * KC + ap];
      pcp[slot] = pc;
    }
  } else {
    const int i = u - 5 * B;
    const float4* x4 = (const float4*)(audio + (size_t)i * D) + lane * 2;
    const float4* y4 = (const float4*)(frame + (size_t)i * D) + lane * 2;
    float4 a0 = x4[0], a1 = x4[1], f0 = y4[0], f1 = y4[1];
    float saf = dot8(a0, a1, f0, f1);
    float sa = dot8(a0, a1, a0, a1);
    float sf = dot8(f0, f1, f0, f1);
    #pragma unroll
    for (int off = 32; off >= 1; off >>= 1) {
      saf += __shfl_xor(saf, off, 64);
      sa  += __shfl_xor(sa, off, 64);
      sf  += __shfl_xor(sf, off, 64);
    }
    if (lane == 0)
      rho0[i] = saf / (fmaxf(sqrtf(sa), 1e-12f) * fmaxf(sqrtf(sf), 1e-12f));
  }
}

// ---------------- K2 v12: 256x256 tile + slab swizzle + COUNTED-vmcnt 3-buffer ring ----------------
// Round-11 finding: FETCH 131->74MB with ZERO duration change — K2 is not
// traffic- or HBM-latency-bound. Rounds 8-11 eliminated barrier count, tile
// size, depth-1 prefetch, and L2 locality. The remaining limiter is the
// per-step serial chain enforced by __syncthreads' implicit vmcnt(0) drain
// (learn_hip m233 "2-phase stall": this structure caps at ~28% of peak).
// v12 = T4 (counted vmcnt, never 0 mid-loop; m218: +38-73%) with minimal
// surgery on the proven v8 body:
//   - 3-buffer LDS ring (96KB), depth-2 prefetch: stage(kt+2) issued at step
//     kt -> two full compute phases to land.
//   - raw `s_barrier` via asm volatile (memory clobber both sides) instead of
//     __syncthreads: no full drain.
//   - loop head: s_waitcnt vmcnt(4) (= stage(kt) retired; stage(kt+1) stays
//     in flight). vmcnt(0) only at kt=15.
// Race proof: stage(kt+2) targets buf[(kt+2)%3] = buf last READ by
// compute(kt-1), separated by the step-kt barrier; per-wave vmcnt(4) +
// barrier ensures ALL waves' stage(kt) landed before any compute(kt) read.
// Counting made exact by draining the invL prologue load (vmcnt(0) once).
// #pragma unroll 1 pins the rolled loop (register protection — rounds
// 1/2/4/5 lesson).
__global__ __launch_bounds__(512) void lse_mfma_kernel(
    const __bf16* __restrict__ Xa, const __bf16* __restrict__ Xf,
    const __bf16* __restrict__ Yf, const __bf16* __restrict__ Ya,
    const float* __restrict__ invdd_f, const float* __restrict__ invdd_a,
    float* __restrict__ sp, float* __restrict__ colsp,
    float* __restrict__ diagAll) {
  __shared__ __bf16 As[3 * 256 * 32];  // 3-buffer ring, 16KB per buffer
  __shared__ __bf16 Bs[3 * 256 * 32];
  __shared__ float invL[260];
  __shared__ float part_s[4 * 256];
  __shared__ float colpart[2][256];

  // ---- XCD slab decomposition (v10: FETCH 131->74MB, keep) ----
  const int b = blockIdx.x;
  const int xcd = b & 7;
  const int bi = b >> 3;               // 0..223 per XCD
  const int slab = bi >> 4;            // 0..13
  const int w = bi & 15;
  const int gs = xcd * 14 + slab;      // global slab 0..111
  const int yy = gs >> 4;              // job slot 0..6
  const int s = gs & 15;
  const int bx = (s >> 2) * 4 + (w >> 2);   // row-tile 0..15
  const int bz = (s & 3) * 4 + (w & 3);     // col-tile 0..15

  const int job = (yy == 0) ? 0 : yy + 1;
  const int i0 = bx * 256;
  const int j0 = bz * 256;

  const __bf16* Ab; const __bf16* Bb; const float* invArr = nullptr;
  if (job == 0)      { Ab = Xa; Bb = Xf; }
  else if (job <= 4) { Ab = Xa; Bb = Yf + (size_t)(job - 2) * B * D;
                       invArr = invdd_f + (job - 2) * B; }
  else               { Ab = Xf; Bb = Ya + (size_t)(job - 5) * B * D;
                       invArr = invdd_a + (job - 5) * B; }
  const bool ii = (job == 0);
  const float invT = 1.f / TEMP;
  const float inv0 = ii ? invT : invArr[0];
  const float MJ = ii ? M_II : M_IP;

  const int tid = threadIdx.x;
  const int wv = tid >> 6;             // 0..7
  const int lane = tid & 63;
  const int wr = (wv >> 2) * 128;      // row half: waves 0-3 / 4-7
  const int wc = (wv & 3) * 64;        // col strip: 4 strips of 64
  const int g = lane >> 4;
  const int cl = lane & 15;

  // per-block density tile (written once; loop barriers separate from use)
  if (!ii && tid < 258) {
    int idx = j0 + tid; if (idx > B - 1) idx = B - 1;
    invL[tid] = invArr[idx];
  }
  // drain the invL global load so in-loop vmcnt counting is exact
  asm volatile("s_waitcnt vmcnt(0)" ::: "memory");

  // staging: XOR-swizzled global source so LDS fragment reads are 2-way (free)
  const int srow = lane >> 2;
  const int skoff = (((lane & 3) ^ ((lane >> 3) & 3)) * 16);
  const int c0row = wv * 16 + srow;
  const char* gA0 = (const char*)Ab + (size_t)(i0 + c0row) * (D * 2) + skoff;
  const char* gA1 = gA0 + (size_t)128 * (D * 2);
  const char* gB0 = (const char*)Bb + (size_t)(j0 + c0row) * (D * 2) + skoff;
  const char* gB1 = gB0 + (size_t)128 * (D * 2);
  __bf16* lA0 = As + wv * 512;
  __bf16* lA1 = As + 4096 + wv * 512;
  __bf16* lB0 = Bs + wv * 512;
  __bf16* lB1 = Bs + 4096 + wv * 512;

  const int csw = (g ^ ((cl >> 1) & 3)) * 8;   // swizzled k-chunk for frag reads
  int aoff[8], boff[4];
  #pragma unroll
  for (int t = 0; t < 8; ++t) aoff[t] = (wr + t * 16 + cl) * 32 + csw;
  #pragma unroll
  for (int t = 0; t < 4; ++t) boff[t] = (wc + t * 16 + cl) * 32 + csw;

  f32x4 acc[8][4];
  #pragma unroll
  for (int ri = 0; ri < 8; ++ri)
    #pragma unroll
    for (int ci = 0; ci < 4; ++ci) acc[ri][ci] = (f32x4){0.f, 0.f, 0.f, 0.f};

  // prologue: stage K-tiles 0,1 into ring buffers 0,1 (8 loads in flight)
  gload_lds16(gA0, lA0);
  gload_lds16(gA1, lA1);
  gload_lds16(gB0, lB0);
  gload_lds16(gB1, lB1);
  gload_lds16(gA0 + 64, lA0 + 8192);
  gload_lds16(gA1 + 64, lA1 + 8192);
  gload_lds16(gB0 + 64, lB0 + 8192);
  gload_lds16(gB1 + 64, lB1 + 8192);

  int cur = 0;          // compute buffer element offset: (kt%3)*8192
  int stg = 16384;      // stage  buffer element offset: ((kt+2)%3)*8192
  #pragma unroll 1
  for (int kt = 0; kt < 16; ++kt) {
    // counted wait: stage(kt) retired (4 oldest); stage(kt+1) stays in flight
    if (kt == 15) asm volatile("s_waitcnt vmcnt(0)" ::: "memory");
    else          asm volatile("s_waitcnt vmcnt(4)" ::: "memory");
    asm volatile("s_barrier" ::: "memory");
    // issue stage(kt+2) early: flies under compute(kt) AND compute(kt+1)
    if (kt <= 13) {
      const int kb = (kt + 2) * 64;
      gload_lds16(gA0 + kb, lA0 + stg);
      gload_lds16(gA1 + kb, lA1 + stg);
      gload_lds16(gB0 + kb, lB0 + stg);
      gload_lds16(gB1 + kb, lB1 + stg);
    }
    bf16x8 af[8], bfr[4];
    #pragma unroll
    for (int t = 0; t < 8; ++t) af[t] = *(const bf16x8*)(As + cur + aoff[t]);
    #pragma unroll
    for (int t = 0; t < 4; ++t) bfr[t] = *(const bf16x8*)(Bs + cur + boff[t]);
    #pragma unroll
    for (int ri = 0; ri < 8; ++ri)
      #pragma unroll
      for (int ci = 0; ci < 4; ++ci)
        acc[ri][ci] = __builtin_amdgcn_mfma_f32_16x16x32_bf16(
            af[ri], bfr[ci], acc[ri][ci], 0, 0, 0);
    cur = (cur == 16384) ? 0 : cur + 8192;
    stg = (stg == 16384) ? 0 : stg + 8192;
  }

  // ---- single epilogue: fixed-max LSE partials for this tile ----
  const bool dtile = (bx == bz);                   // diagonal intersects tile?
  const int co = (j0 < i0) ? 1 : 0;                // uniform density shift
  float sacc[8][4];
  float csum[4] = {0.f, 0.f, 0.f, 0.f};
  #pragma unroll
  for (int ri = 0; ri < 8; ++ri) {
    #pragma unroll
    for (int v = 0; v < 4; ++v) {
      const int gi = i0 + wr + ri * 16 + g * 4 + v;
      float acc4 = 0.f;
      #pragma unroll
      for (int ci = 0; ci < 4; ++ci) {
        const int jloc = wc + ci * 16 + cl;
        const int gj = j0 + jloc;
        float sc;
        if (ii) sc = invT;
        else if (!dtile) sc = invL[jloc + co];
        else sc = (gj == gi) ? inv0 : invL[(gj < gi) ? (jloc + 1) : jloc];
        float lv = acc[ri][ci][v] * sc;
        if (dtile && gj == gi) diagAll[(size_t)job * B + gi] = lv;
        float ev = __expf(lv - MJ);
        acc4 += ev;
        if (ii) csum[ci] += ev;
      }
      sacc[ri][v] = acc4;
    }
  }
  if (ii) {
    // column partials: reduce over the wave's 128 rows (g-groups), then
    // combine the two row-half wave sets via LDS.
    #pragma unroll
    for (int ci = 0; ci < 4; ++ci) {
      csum[ci] += __shfl_xor(csum[ci], 16, 64);
      csum[ci] += __shfl_xor(csum[ci], 32, 64);
    }
    if (g == 0) {
      #pragma unroll
      for (int ci = 0; ci < 4; ++ci)
        colpart[wv >> 2][wc + ci * 16 + cl] = csum[ci];
    }
    __syncthreads();
    if (tid < 256)
      colsp[(size_t)bx * B + j0 + tid] =
          colpart[0][tid] + colpart[1][tid];
  }

  // row-LSE partials: 16-lane column reduce -> LDS -> sum 4 col strips
  #pragma unroll
  for (int ri = 0; ri < 8; ++ri) {
    #pragma unroll
    for (int v = 0; v < 4; ++v) {
      float s2 = sacc[ri][v];
      #pragma unroll
      for (int off = 8; off >= 1; off >>= 1) s2 += __shfl_xor(s2, off, 64);
      if (cl == 0) part_s[(wv & 3) * 256 + wr + ri * 16 + g * 4 + v] = s2;
    }
  }
  __syncthreads();
  if (tid < 256) {
    size_t o = ((size_t)job * 16 + bz) * B + i0 + tid;
    sp[o] = part_s[tid] + part_s[256 + tid] + part_s[512 + tid] + part_s[768 + tid];
  }
}

// ---------------- K3: fused LSE-merge (blocks 0..127) + stable rank (128..255) ----------------
__global__ __launch_bounds__(256) void merge_rank_kernel(
    const float* __restrict__ sp, const float* __restrict__ colsp,
    const float* __restrict__ diagAll, const float* __restrict__ rho0,
    const float* __restrict__ pcp,
    float* __restrict__ lossAll, int* __restrict__ rankArr,
    float* __restrict__ srho) {
  __shared__ float lr[B];
  __shared__ float cnt[256];
  const int blk = blockIdx.x;
  const int t = threadIdx.x;
  if (blk < 128) {
    int idx = blk * 256 + t;          // 0 .. 8*B-1
    int job = idx >> 12;
    int i = idx & (B - 1);
    if (job == 1) {
      // f2v inst-inst: column-LSE of job0's matrix; diag equals job0's diag
      float stot = 0.f;
      #pragma unroll
      for (int x = 0; x < 16; ++x) stot += colsp[(size_t)x * B + i];
      lossAll[idx] = M_II + logf(stot) - diagAll[i];
    } else {
      const float* s16 = sp + (size_t)job * 16 * B + i;
      float stot = 0.f;
      #pragma unroll
      for (int x = 0; x < 16; ++x) stot += s16[(size_t)x * B];
      float MJ = (job < 2) ? M_II : M_IP;
      lossAll[idx] = MJ + logf(stot) - diagAll[(size_t)job * B + i];
    }
  } else {
    // rank: 128 blocks x 32 i's, 8-way j-split (512 j's per thread)
    const int base = (blk - 128) * 32;
    const int il = t & 31;
    const int i = base + il;
    const int jlo = (t >> 5) * 512;
    for (int k = t; k < B; k += 256)
      lr[k] = rho0[k] - pcp[k] - pcp[B + k] - pcp[2 * B + k];
    __syncthreads();
    float my = lr[i];
    int rk = 0;
    #pragma unroll 8
    for (int j = jlo; j < jlo + 512; ++j) {
      float v = lr[j];
      rk += (v < my) || (v == my && j < i);   // stable: ties by index
    }
    cnt[t] = (float)rk;
    __syncthreads();
    if (t < 32) {
      int r = 0;
      #pragma unroll
      for (int s = 0; s < 8; ++s) r += (int)cnt[s * 32 + t];
      rankArr[i] = r;
      srho[r] = my;
    }
  }
}

// ---------------- K4: stats + pdf + scan + weights + final (one block, 1024 thr) ----------------
__global__ __launch_bounds__(1024) void cdf_final_kernel(
    const float* __restrict__ srho, const int* __restrict__ rankArr,
    const float* __restrict__ lossAll, float* __restrict__ out) {
  __shared__ float pdf[B];
  __shared__ float wred[16], wr1[16], wr2[16];
  __shared__ float wexc[16];
  __shared__ float mv[3];              // mu, sigma, ylast
  const int t = threadIdx.x;
  const int lane = t & 63;
  const int wid = t >> 6;

  float4 sv = *reinterpret_cast<const float4*>(srho + (size_t)t * 4);
  // ---- mean ----
  float s = sv.x + sv.y + sv.z + sv.w;
  #pragma unroll
  for (int off = 32; off >= 1; off >>= 1) s += __shfl_xor(s, off, 64);
  if (lane == 0) wred[wid] = s;
  __syncthreads();
  if (t == 0) {
    float tot = 0.f;
    #pragma unroll
    for (int w = 0; w < 16; ++w) tot += wred[w];
    mv[0] = tot / (float)B;
  }
  __syncthreads();
  const float mean = mv[0];
  __syncthreads();
  // ---- std ----
  float dx = sv.x - mean, dy = sv.y - mean, dz = sv.z - mean, dw = sv.w - mean;
  float v = dx * dx + dy * dy + dz * dz + dw * dw;
  #pragma unroll
  for (int off = 32; off >= 1; off >>= 1) v += __shfl_xor(v, off, 64);
  if (lane == 0) wred[wid] = v;
  __syncthreads();
  if (t == 0) {
    float tot = 0.f;
    #pragma unroll
    for (int w = 0; w < 16; ++w) tot += wred[w];
    float sd = sqrtf(tot / (float)B);
    mv[0] = mean + 0.3f * sd;          // mu = mean + DELTA*std
    mv[1] = sd * 1.41421356237f;       // sigma = std*sqrt(KA)
  }
  __syncthreads();
  const float mu = mv[0], sg = mv[1];
  const float c = 1.f / (2.5066282746310002f * sg);
  // ---- pdf (in regs) + two-level inclusive scan ----
  float p[4];
  {
    float z0 = (sv.x - mu) / sg; p[0] = expf(-0.5f * z0 * z0) * c;
    float z1 = (sv.y - mu) / sg; p[1] = expf(-0.5f * z1 * z1) * c;
    float z2 = (sv.z - mu) / sg; p[2] = expf(-0.5f * z2 * z2) * c;
    float z3 = (sv.w - mu) / sg; p[3] = expf(-0.5f * z3 * z3) * c;
  }
  float chunk = p[0] + p[1] + p[2] + p[3];
  float incl = chunk;
  #pragma unroll
  for (int d = 1; d < 64; d <<= 1) {
    float n = __shfl_up(incl, d, 64);
    if (lane >= d) incl += n;
  }
  if (lane == 63) wred[wid] = incl;
  __syncthreads();
  if (t == 0) {
    float run = 0.f;
    #pragma unroll
    for (int w = 0; w < 16; ++w) { wexc[w] = run; run += wred[w]; }
    mv[2] = run;                       // ylast = total sum
  }
  __syncthreads();
  float run = wexc[wid] + (incl - chunk);
  #pragma unroll
  for (int e = 0; e < 4; ++e) { run += p[e]; pdf[t * 4 + e] = run; }
  const float ylast = mv[2];
  __syncthreads();
  // ---- final: weights from rank, weighted means, scalar out ----
  int4 rks = *reinterpret_cast<const int4*>(rankArr + (size_t)t * 4);
  float sw = 0.f, s1 = 0.f, s2 = 0.f;
  #pragma unroll
  for (int e = 0; e < 4; ++e) {
    const int i = t * 4 + e;
    const int rk = (e == 0) ? rks.x : (e == 1) ? rks.y : (e == 2) ? rks.z : rks.w;
    float wi = pdf[rk] / ylast;
    float lpv = lossAll[2 * B + i] * (1.f / 27.f) + lossAll[3 * B + i] * (1.f / 9.f)
              + lossAll[4 * B + i] * (1.f / 3.f);
    float lpf = lossAll[5 * B + i] * (1.f / 27.f) + lossAll[6 * B + i] * (1.f / 9.f)
              + lossAll[7 * B + i] * (1.f / 3.f);
    sw += wi;
    s1 += wi * (lossAll[i] + lpv);
    s2 += wi * (lossAll[B + i] + lpf);
  }
  #pragma unroll
  for (int off = 32; off >= 1; off >>= 1) {
    sw += __shfl_xor(sw, off, 64);
    s1 += __shfl_xor(s1, off, 64);
    s2 += __shfl_xor(s2, off, 64);
  }
  if (lane == 0) { wred[wid] = sw; wr1[wid] = s1; wr2[wid] = s2; }
  __syncthreads();
  if (t == 0) {
    float tw = 0.f, t1 = 0.f, t2 = 0.f;
    #pragma unroll
    for (int w = 0; w < 16; ++w) { tw += wred[w]; t1 += wr1[w]; t2 += wr2[w]; }
    out[0] = t1 / tw + t2 / tw;
  }
}

extern "C" void kernel_launch(void* const* d_in, const int* in_sizes, int n_in,
                              void* d_out, int out_size, void* d_ws, size_t ws_size,
                              hipStream_t stream) {
  const float* audio  = (const float*)d_in[0];
  const float* frame  = (const float*)d_in[1];
  const float* a_cent = (const float*)d_in[2];
  const float* a_dens = (const float*)d_in[3];
  const float* f_cent = (const float*)d_in[4];
  const float* f_dens = (const float*)d_in[5];
  const int* vidx  = (const int*)d_in[6];
  const int* a_i2c = (const int*)d_in[7];
  const int* f_i2c = (const int*)d_in[8];
  float* out = (float*)d_out;

  const size_t BD = (size_t)B * D;
  char* base = (char*)d_ws;
  __bf16* Xa = (__bf16*)base;              base += BD * 2;
  __bf16* Xf = (__bf16*)base;              base += BD * 2;
  __bf16* Yf = (__bf16*)base;              base += 3 * BD * 2;
  __bf16* Ya = (__bf16*)base;              base += 3 * BD * 2;
  float* invdd_f = (float*)base;           base += 3 * B * 4;
  float* invdd_a = (float*)base;           base += 3 * B * 4;
  float* rho0    = (float*)base;           base += B * 4;
  float* pcp     = (float*)base;           base += 3 * B * 4;
  float* sp      = (float*)base;           base += 128 * B * 4;
  float* colsp   = (float*)base;           base += 16 * B * 4;
  float* diagAll = (float*)base;           base += 8 * B * 4;
  float* lossAll = (float*)base;           base += 8 * B * 4;
  float* srho    = (float*)base;           base += B * 4;
  int*   rankArr = (int*)base;

  prep_kernel<<<(6 * B) / 4, 256, 0, stream>>>(audio, frame, a_cent, a_dens,
                                               f_cent, f_dens, vidx, a_i2c, f_i2c,
                                               Xa, Xf, Yf, Ya, invdd_f, invdd_a,
                                               rho0, pcp);

  lse_mfma_kernel<<<1792, 512, 0, stream>>>(Xa, Xf, Yf, Ya, invdd_f, invdd_a,
                                            sp, colsp, diagAll);

  merge_rank_kernel<<<256, 256, 0, stream>>>(sp, colsp, diagAll, rho0, pcp,
                                             lossAll, rankArr, srho);
  cdf_final_kernel<<<1, 1024, 0, stream>>>(srho, rankArr, lossAll, out);
}